// Round 17
// baseline (108.695 us; speedup 1.0000x reference)
//
#include <hip/hip_runtime.h>
#include <hip/hip_bf16.h>
#include <stdint.h>

// Problem constants: B=2, T=1024, D=1024, N=16
#define TT 1024
#define BB 2
#define DD 1024
#define NN 16
#define NCH 256  // chunks
#define LCH 4    // chunk length (NCH*LCH == TT)

#define K_STEEP 10.0f
#define V_TH_MIN 0.1f
#define L2E 1.44269504088896f

#if defined(__has_builtin)
#if __has_builtin(__builtin_amdgcn_exp2f)
#define EXP2(x) __builtin_amdgcn_exp2f(x)
#endif
#endif
#ifndef EXP2
#define EXP2(x) exp2f(x)
#endif

typedef __bf16 bf16x8 __attribute__((ext_vector_type(8)));
typedef float f32x4 __attribute__((ext_vector_type(4)));

__device__ __forceinline__ short f2bf(float f) {
    union { float f; unsigned u; } c; c.f = f;
    unsigned r = (c.u + 0x7fffu + ((c.u >> 16) & 1u)) >> 16;
    return (short)r;
}
__device__ __forceinline__ float bf2f(short s) {
    union { unsigned u; float f; } c;
    c.u = ((unsigned)(unsigned short)s) << 16;
    return c.f;
}

__device__ __forceinline__ void gload_lds16(const void* g, void* l) {
    __builtin_amdgcn_global_load_lds(
        (const __attribute__((address_space(1))) void*)g,
        (__attribute__((address_space(3))) void*)l, 16, 0, 0);
}

// ---------------------------------------------------------------------------
// bf16 MFMA GEMM: C[M][N] = A[M][K] @ BT[N][K]^T  (+ epilogue)
// Tile BM x 128, BK=64, 256 threads.  LDS rows 128B (64 bf16).
// EPI 2: fp32 store of (v - sub[row*ldc+col])
// EPI 3: bf16 stores: xb[row*DD+col] (col<DD) AND xzT[col*2048+row] (packed)
// EPI 4: bf16 store of softplus(v + bias[ROW]) into xb_out[row*ldc+col]
// FUSE_BC: blocks with blockIdx.x == gridDim.x-1 compute bc rows, store bf16
//   SWIZZLED: bcs[((b*4+j)*256+c)*32 + col], j=t&3, c=t>>2.
// ---------------------------------------------------------------------------
template<int BM, int EPI, bool FUSE_BC>
__global__ __launch_bounds__(256) void gemm_mfma(
    const short* __restrict__ A, int lda,
    const short* __restrict__ BT, int ldb,
    float* __restrict__ C, int ldc,
    int M, int Ncols, int K,
    const float* __restrict__ bias,
    const float* __restrict__ sub,
    short* __restrict__ xb_out,
    short* __restrict__ xzT_out,
    const short* __restrict__ WbcT,
    short* __restrict__ bcs)
{
    constexpr int RI = BM / 32;          // row frags per wave
    __shared__ short As[BM * 64];        // [row][64k], 128B rows
    __shared__ short Bs[128 * 64];       // [n][64k]

    const int tid = threadIdx.x;
    const int wave = tid >> 6, lane = tid & 63;
    const int kk = (lane >> 4) * 8;
    const int r16 = lane & 15;
    const int wr = wave >> 1, wc = wave & 1;

    if (FUSE_BC && blockIdx.x == gridDim.x - 1) {
        // ---- bc path: 32 rows x 32 cols, BK=64 ----
        const int bm2 = blockIdx.y * 32;
        f32x4 acc2 = {};
        for (int k0 = 0; k0 < K; k0 += 64) {
            int off = tid * 16;
            int row = off >> 7;            // 128B per row (64 bf16)
            int ke  = (off & 127) >> 1;
            gload_lds16(A + (size_t)(bm2 + row) * lda + k0 + ke, (char*)As + off);
            gload_lds16(WbcT + (size_t)row * K + k0 + ke, (char*)Bs + off);
            __syncthreads();
            bf16x8 alo = *(const bf16x8*)&As[(wr * 16 + r16) * 64 + kk];
            bf16x8 ahi = *(const bf16x8*)&As[(wr * 16 + r16) * 64 + kk + 32];
            bf16x8 blo = *(const bf16x8*)&Bs[(wc * 16 + r16) * 64 + kk];
            bf16x8 bhi = *(const bf16x8*)&Bs[(wc * 16 + r16) * 64 + kk + 32];
            acc2 = __builtin_amdgcn_mfma_f32_16x16x32_bf16(alo, blo, acc2, 0, 0, 0);
            acc2 = __builtin_amdgcn_mfma_f32_16x16x32_bf16(ahi, bhi, acc2, 0, 0, 0);
            __syncthreads();
        }
        #pragma unroll
        for (int g = 0; g < 4; g++) {
            int row = bm2 + wr * 16 + (lane >> 4) * 4 + g;
            int col = wc * 16 + r16;
            int bb = row >> 10, t = row & 1023;
            int j = t & 3, c = t >> 2;
            bcs[(size_t)(((bb << 2) | j) * NCH + c) * 32 + col] = f2bf(acc2[g]);
        }
        return;
    }

    const int bm = blockIdx.y * BM, bn = blockIdx.x * 128;
    f32x4 acc[RI][4] = {};

    for (int k0 = 0; k0 < K; k0 += 64) {
        // stage B tile: 16384B, 4 x 16B per thread
        #pragma unroll
        for (int it = 0; it < 4; it++) {
            int off = it * 4096 + tid * 16;
            int row = off >> 7;             // 128B per row (64 bf16)
            int ke  = (off & 127) >> 1;
            gload_lds16(BT + (size_t)(bn + row) * ldb + k0 + ke, (char*)Bs + off);
        }
        // stage A tile: BM*128 bytes (BM=32 -> 4096B, 1 x 16B per thread)
        if (tid < BM * 8) {
            int off = tid * 16;
            int row = off >> 7;
            int ke  = (off & 127) >> 1;
            gload_lds16(A + (size_t)(bm + row) * lda + k0 + ke, (char*)As + off);
        }
        __syncthreads();

        #pragma unroll
        for (int ks = 0; ks < 64; ks += 32) {
            bf16x8 a[RI], b[4];
            #pragma unroll
            for (int i = 0; i < RI; i++)
                a[i] = *(const bf16x8*)&As[(wr * (BM / 2) + i * 16 + r16) * 64 + ks + kk];
            #pragma unroll
            for (int j = 0; j < 4; j++)
                b[j] = *(const bf16x8*)&Bs[(wc * 64 + j * 16 + r16) * 64 + ks + kk];
            #pragma unroll
            for (int i = 0; i < RI; i++)
                #pragma unroll
                for (int j = 0; j < 4; j++)
                    acc[i][j] = __builtin_amdgcn_mfma_f32_16x16x32_bf16(
                        a[i], b[j], acc[i][j], 0, 0, 0);
        }
        __syncthreads();
    }

    // epilogue: C/D layout col = lane&15, row = (lane>>4)*4 + reg (m89/m91)
    #pragma unroll
    for (int i = 0; i < RI; i++) {
        #pragma unroll
        for (int j = 0; j < 4; j++) {
            int row0 = bm + wr * (BM / 2) + i * 16 + (lane >> 4) * 4;
            int col = bn + wc * 64 + j * 16 + r16;
            if (EPI == 3) {
                short4 p;
                #pragma unroll
                for (int g = 0; g < 4; g++) {
                    short h = f2bf(acc[i][j][g]);
                    ((short*)&p)[g] = h;
                    if (col < DD) xb_out[(size_t)(row0 + g) * DD + col] = h;
                }
                *(short4*)&xzT_out[(size_t)col * 2048 + row0] = p;
            } else {
                #pragma unroll
                for (int g = 0; g < 4; g++) {
                    int row = row0 + g;
                    float v = acc[i][j][g];
                    if (EPI == 4) {
                        v += bias[row];
                        v = fmaxf(v, 0.f) + log1pf(__expf(-fabsf(v)));
                        xb_out[(size_t)row * ldc + col] = f2bf(v);
                    } else {
                        if (EPI == 2) v -= sub[(size_t)row * ldc + col];
                        C[(size_t)row * ldc + col] = v;
                    }
                }
            }
        }
    }
}

// ---------------------------------------------------------------------------
// 32x32 fp32->bf16 transpose tile (shared helper for prep kernel)
// ---------------------------------------------------------------------------
__device__ __forceinline__ void tr_tile(
    const float* __restrict__ W, short* __restrict__ WT,
    int K, int N, int k0, int n0, int tid)
{
    __shared__ float t[32][33];
    int r = tid >> 3, q = tid & 7;
    float4 v = *(const float4*)&W[(size_t)(k0 + r) * N + n0 + q * 4];
    t[r][q * 4 + 0] = v.x; t[r][q * 4 + 1] = v.y;
    t[r][q * 4 + 2] = v.z; t[r][q * 4 + 3] = v.w;
    __syncthreads();
    short4 o = { f2bf(t[q * 4 + 0][r]), f2bf(t[q * 4 + 1][r]),
                 f2bf(t[q * 4 + 2][r]), f2bf(t[q * 4 + 3][r]) };
    *(short4*)&WT[(size_t)(n0 + r) * K + k0 + q * 4] = o;
}

// ---------------------------------------------------------------------------
// One-shot prep: all fp32->bf16 converts/transposes in a single launch.
// ---------------------------------------------------------------------------
__global__ __launch_bounds__(256) void prep_all(
    const float* __restrict__ H,    short* __restrict__ Hb,
    const float* __restrict__ W_xz, short* __restrict__ WxzT,
    const float* __restrict__ W_dt, short* __restrict__ WdtT,
    const float* __restrict__ W_out,short* __restrict__ WoutT,
    const float* __restrict__ W_B,  const float* __restrict__ W_C,
    short* __restrict__ WbcT)
{
    int bid = blockIdx.x, tid = threadIdx.x;
    if (bid < 2048) {
        int i = bid * 1024 + tid * 4;
        float4 v = *(const float4*)&H[i];
        short4 o = { f2bf(v.x), f2bf(v.y), f2bf(v.z), f2bf(v.w) };
        *(short4*)&Hb[i] = o;
    } else if (bid < 4096) {
        int t = bid - 2048;                       // 64 n-tiles x 32 k-tiles
        tr_tile(W_xz, WxzT, DD, 2 * DD, (t >> 6) * 32, (t & 63) * 32, tid);
    } else if (bid < 5120) {
        int t = bid - 4096;
        tr_tile(W_dt, WdtT, DD, DD, (t >> 5) * 32, (t & 31) * 32, tid);
    } else if (bid < 6144) {
        int t = bid - 5120;
        tr_tile(W_out, WoutT, DD, DD, (t >> 5) * 32, (t & 31) * 32, tid);
    } else {
        int g = (bid - 6144) * 256 + tid;         // 0..32767
        int k = g & (DD - 1);
        int n = g >> 10;
        float v = (n < 16) ? W_B[(size_t)k * NN + n]
                           : W_C[(size_t)k * NN + n - 16];
        WbcT[(size_t)n * DD + k] = f2bf(v);
    }
}

// ---------------------------------------------------------------------------
// bf16 transpose: gT[1024 d][2048 bt] -> gb[2048 bt][1024 d].  64x64 tiles.
// ---------------------------------------------------------------------------
__global__ __launch_bounds__(256) void tr_g(
    const short* __restrict__ gT, short* __restrict__ gb)
{
    __shared__ short L[64][72];   // 72-short stride keeps 16B alignment
    const int bt0 = blockIdx.x * 64, d0 = blockIdx.y * 64;
    const int tid = threadIdx.x;
    const int r = tid >> 3, c8 = (tid & 7) * 8;
    #pragma unroll
    for (int p = 0; p < 2; p++) {
        int dd = r + p * 32;
        *(int4*)&L[dd][c8] = *(const int4*)&gT[(size_t)(d0 + dd) * 2048 + bt0 + c8];
    }
    __syncthreads();
    #pragma unroll
    for (int p = 0; p < 2; p++) {
        int tb = r + p * 32;
        short tmp[8];
        #pragma unroll
        for (int k = 0; k < 8; k++) tmp[k] = L[c8 + k][tb];
        *(int4*)&gb[(size_t)(bt0 + tb) * DD + d0 + c8] = *(int4*)&tmp[0];
    }
}

// ---------------------------------------------------------------------------
// Fused scan v8: LCH=4/NCH=256, swizzled bf16 bc, bf16 dt, native exp2,
// and NO phase-3 replay: phase 1 records yloc_j = C_j . s_local_j and cdt_j;
// phase 3 adds the chain-free correction
//   y_j = yloc_j + sum_n C_j[n] * exp2(a2[n]*cdt_j) * Sinit[n].
// (+8 VGPR vs v7 -- safe at LCH=4; numerics proven in r13.)
// Block: 512 threads = 2 d-lanes x 256 chunks; grid (DD/2, BB) = 1024 blocks
// -> 4 blocks/CU (LDS 40960B x 4 = 160KiB exact), 8 waves/SIMD.
// ---------------------------------------------------------------------------
__global__ __launch_bounds__(512) void scan_fused8(
    const short* __restrict__ dtb16,  // [1024 d][2048 bt] bf16 (post-softplus)
    const short* __restrict__ xzT,    // [2048 e][2048 bt] bf16
    const short* __restrict__ bcs,    // [b][4][256][32] bf16 (B|C swizzled)
    const float* __restrict__ A_log,  // [1024][16]
    const float* __restrict__ D_skip,
    const float* __restrict__ v_th,
    short* __restrict__ gT)           // [1024 d][2048 bt] bf16
{
    __shared__ float Ls[512 * 17];        // 34816 B; Sinit in-place
    __shared__ float Sd[512];             // 2048 B: per-chunk sum(dt)
    __shared__ float Gp[16][2][16];       // 2048 B: group decay, then Gi in-place
    __shared__ float Gl[16][2][16];       // 2048 B: group local state
                                          // total 40960 B -> 4 blocks/CU

    const int tid = threadIdx.x;
    const int dl = tid & 1;
    const int c  = tid >> 1;               // chunk 0..255
    const int d  = blockIdx.x * 2 + dl;
    const int b  = blockIdx.y;
    const int R0 = b * TT + c * LCH;        // global bt base

    float a2[NN];
    #pragma unroll
    for (int n = 0; n < NN; n++)
        a2[n] = -__expf(A_log[(size_t)d * NN + n]) * L2E;

    // contiguous per-thread stream preloads (8B dt, 8B x, 8B z)
    short dth[LCH];
    *(int2*)&dth[0] = *(const int2*)&dtb16[(size_t)d * 2048 + R0];
    float dtv[LCH];
    #pragma unroll
    for (int j = 0; j < LCH; j++) dtv[j] = bf2f(dth[j]);
    short xv[LCH], zv[LCH];
    *(int2*)&xv[0] = *(const int2*)&xzT[(size_t)d * 2048 + R0];
    *(int2*)&zv[0] = *(const int2*)&xzT[(size_t)(DD + d) * 2048 + R0];

    // ---- phase 1: local chunk scan (s0 = 0); record yloc + cumulative dt ---
    float s[NN];
    #pragma unroll
    for (int n = 0; n < NN; n++) s[n] = 0.f;
    float sum_dt = 0.f;
    float cdt[LCH], yloc[LCH];

    #pragma unroll
    for (int j = 0; j < LCH; j++) {
        float dt = dtv[j];
        float dtx = dt * bf2f(xv[j]);
        sum_dt += dt;
        cdt[j] = sum_dt;
        const short* bp = &bcs[(size_t)(((b << 2) | j) * NCH + c) * 32];
        short bB[NN], bC[NN];
        *(int4*)&bB[0] = *(const int4*)&bp[0];
        *(int4*)&bB[8] = *(const int4*)&bp[8];
        *(int4*)&bC[0] = *(const int4*)&bp[16];
        *(int4*)&bC[8] = *(const int4*)&bp[24];
        float y = 0.f;
        #pragma unroll
        for (int n = 0; n < NN; n++) {
            float dec = EXP2(a2[n] * dt);
            s[n] = fmaf(dec, s[n], dtx * bf2f(bB[n]));
            y = fmaf(s[n], bf2f(bC[n]), y);
        }
        yloc[j] = y;
    }
    #pragma unroll
    for (int n = 0; n < NN; n++) Ls[tid * 17 + n] = s[n];
    Sd[tid] = sum_dt;
    __syncthreads();

    // ---- phase 2: hierarchical combine (16 groups x 16 chunks) ----
    {
        int dl2 = tid & 1, n2 = (tid >> 1) & 15, sg = tid >> 5;
        float a2n = -__expf(A_log[(size_t)(blockIdx.x * 2 + dl2) * NN + n2]) * L2E;
        float Pg = 1.f, Lg = 0.f;
        for (int k = 0; k < 16; k++) {
            int lt = (sg * 16 + k) * 2 + dl2;
            float P = EXP2(a2n * Sd[lt]);
            float L = Ls[lt * 17 + n2];
            Lg = fmaf(P, Lg, L);
            Pg *= P;
        }
        Gp[sg][dl2][n2] = Pg; Gl[sg][dl2][n2] = Lg;
        __syncthreads();
        if (tid < 32) {
            int dl3 = tid & 1, n3 = tid >> 1;
            float Sg = 0.f;
            for (int g = 0; g < 16; g++) {
                float Pgv = Gp[g][dl3][n3];
                Gp[g][dl3][n3] = Sg;          // Gi overwrites Gp (read-first)
                Sg = fmaf(Pgv, Sg, Gl[g][dl3][n3]);
            }
        }
        __syncthreads();
        float ss = Gp[sg][dl2][n2];           // group-init state
        for (int k = 0; k < 16; k++) {
            int lt = (sg * 16 + k) * 2 + dl2;
            float P = EXP2(a2n * Sd[lt]);
            float L = Ls[lt * 17 + n2];
            Ls[lt * 17 + n2] = ss;            // Sinit overwrites (read-first)
            ss = fmaf(P, ss, L);
        }
    }
    __syncthreads();

    // ---- phase 3: chain-free init-correction + gate epilogue ----
    #pragma unroll
    for (int n = 0; n < NN; n++) s[n] = Ls[tid * 17 + n];   // Sinit

    const float dsk = D_skip[d];
    const float vth = fmaxf(v_th[d], V_TH_MIN);
    const float KL2 = K_STEEP * L2E;
    short gvv[LCH];

    #pragma unroll
    for (int j = 0; j < LCH; j++) {
        const short* bp = &bcs[(size_t)(((b << 2) | j) * NCH + c) * 32];
        short bC[NN];
        *(int4*)&bC[0] = *(const int4*)&bp[16];
        *(int4*)&bC[8] = *(const int4*)&bp[24];
        float y = yloc[j];
        #pragma unroll
        for (int n = 0; n < NN; n++) {
            float e = EXP2(a2[n] * cdt[j]);
            y = fmaf(bf2f(bC[n]) * e, s[n], y);
        }
        float x = bf2f(xv[j]);
        float z = bf2f(zv[j]);
        y = fmaf(dsk, x, y);
        float sp = 1.f / (1.f + EXP2(-KL2 * (y - vth)));
        float sz = z / (1.f + EXP2(-z * L2E));
        gvv[j] = f2bf(y * sp * sz);
    }

    // one 8B contiguous store per thread
    *(int2*)&gT[(size_t)d * 2048 + R0] = *(const int2*)&gvv[0];
}

// ---------------------------------------------------------------------------
extern "C" void kernel_launch(void* const* d_in, const int* in_sizes, int n_in,
                              void* d_out, int out_size, void* d_ws, size_t ws_size,
                              hipStream_t stream) {
    const float* H      = (const float*)d_in[0];   // (2,1024,1024)
    const float* W_xz   = (const float*)d_in[1];   // (1024,2048)
    const float* W_dt   = (const float*)d_in[2];   // (1024,1024)
    const float* b_dt   = (const float*)d_in[3];   // (1024,)
    const float* A_log  = (const float*)d_in[4];   // (1024,16)
    const float* W_B    = (const float*)d_in[5];   // (1024,16)
    const float* W_C    = (const float*)d_in[6];   // (1024,16)
    const float* D_skip = (const float*)d_in[7];   // (1024,)
    const float* W_out  = (const float*)d_in[8];   // (1024,1024)
    const float* v_th   = (const float*)d_in[9];   // (1024,)
    float* out = (float*)d_out;

    // flat ws layout (~40 MB of 268 MB) — no aliasing
    short* p16   = (short*)d_ws;
    short* dtb16 = p16;                // 1024*2048 = 2097152 s (bf16 dt)
    short* bcs   = dtb16 + 2097152;    // 2*4*256*32 = 65536 s (bf16, swizzled)
    short* xzT   = bcs   + 65536;      // 2048*2048 s  (xT | zT)
    short* xb    = xzT   + 4194304;    // 2048*1024 s  (x row-major, for G2)
    short* Hb    = xb    + 2097152;    // 2097152 s
    short* WxzT  = Hb    + 2097152;    // 2097152 s
    short* WdtT  = WxzT  + 2097152;    // 1048576 s
    short* WoutT = WdtT  + 1048576;    // 1048576 s
    short* WbcT  = WoutT + 1048576;    // 32768 s
    short* gT    = WbcT  + 32768;      // 1024*2048 s (g transposed)
    short* gb    = gT    + 2097152;    // 2048*1024 s (g row-major)

    const int M = BB * TT;  // 2048

    // 0) all converts in one launch
    prep_all<<<6272, 256, 0, stream>>>(
        H, Hb, W_xz, WxzT, W_dt, WdtT, W_out, WoutT, W_B, W_C, WbcT);
    // 1) xz = H @ W_xz: writes xb + xzT, + swizzled bf16 bc
    gemm_mfma<32, 3, true><<<dim3(17, M / 32), 256, 0, stream>>>(
        Hb, DD, WxzT, DD, nullptr, 0, M, 2 * DD, DD,
        nullptr, nullptr, xb, xzT, WbcT, bcs);
    // 2) dtb16 = softplus(W_dt^T @ x^T + b_dt[row]) stored bf16
    gemm_mfma<32, 4, false><<<dim3(M / 128, DD / 32), 256, 0, stream>>>(
        WdtT, DD, xb, DD, nullptr, M, DD, M, DD,
        b_dt, nullptr, dtb16, nullptr, nullptr, nullptr);
    // 3) fused chunked scan (bf16 dt, chain-free phase 3, native exp2)
    scan_fused8<<<dim3(DD / 2, BB), 512, 0, stream>>>(
        dtb16, xzT, bcs, A_log, D_skip, v_th, gT);
    // 3b) transpose gT -> gb (row-major for G3's A operand)
    tr_g<<<dim3(2048 / 64, DD / 64), 256, 0, stream>>>(gT, gb);
    // 4) out = g @ W_out - H
    gemm_mfma<32, 2, false><<<dim3(DD / 128, M / 32), 256, 0, stream>>>(
        gb, DD, WoutT, DD, out, DD, M, DD, DD,
        nullptr, H, nullptr, nullptr, nullptr, nullptr);
}

// Round 18
// 104.100 us; speedup vs baseline: 1.0441x; 1.0441x over previous
//
#include <hip/hip_runtime.h>
#include <hip/hip_bf16.h>
#include <stdint.h>

// Problem constants: B=2, T=1024, D=1024, N=16
#define TT 1024
#define BB 2
#define DD 1024
#define NN 16
#define NCH 256  // chunks
#define LCH 4    // chunk length (NCH*LCH == TT)

#define K_STEEP 10.0f
#define V_TH_MIN 0.1f
#define L2E 1.44269504088896f

#if defined(__has_builtin)
#if __has_builtin(__builtin_amdgcn_exp2f)
#define EXP2(x) __builtin_amdgcn_exp2f(x)
#endif
#endif
#ifndef EXP2
#define EXP2(x) exp2f(x)
#endif

typedef __bf16 bf16x8 __attribute__((ext_vector_type(8)));
typedef float f32x4 __attribute__((ext_vector_type(4)));

__device__ __forceinline__ short f2bf(float f) {
    union { float f; unsigned u; } c; c.f = f;
    unsigned r = (c.u + 0x7fffu + ((c.u >> 16) & 1u)) >> 16;
    return (short)r;
}
__device__ __forceinline__ float bf2f(short s) {
    union { unsigned u; float f; } c;
    c.u = ((unsigned)(unsigned short)s) << 16;
    return c.f;
}

__device__ __forceinline__ void gload_lds16(const void* g, void* l) {
    __builtin_amdgcn_global_load_lds(
        (const __attribute__((address_space(1))) void*)g,
        (__attribute__((address_space(3))) void*)l, 16, 0, 0);
}

// ---------------------------------------------------------------------------
// bf16 MFMA GEMM: C[M][N] = A[M][K] @ BT[N][K]^T  (+ epilogue)
// Tile BM x 128, BK=64, 256 threads.  LDS rows 128B (64 bf16).
// EPI 2: fp32 store of (v - sub[row*ldc+col])
// EPI 3: bf16 stores: xb[row*DD+col] (col<DD) AND xzT[col*2048+row] (packed)
// EPI 4: fp32 store of softplus(v + bias[ROW])   (for transposed-output GEMM)
// FUSE_BC: blocks with blockIdx.x == gridDim.x-1 compute bc rows, store bf16
//   SWIZZLED: bcs[((b*4+j)*256+c)*32 + col], j=t&3, c=t>>2.
// ---------------------------------------------------------------------------
template<int BM, int EPI, bool FUSE_BC>
__global__ __launch_bounds__(256) void gemm_mfma(
    const short* __restrict__ A, int lda,
    const short* __restrict__ BT, int ldb,
    float* __restrict__ C, int ldc,
    int M, int Ncols, int K,
    const float* __restrict__ bias,
    const float* __restrict__ sub,
    short* __restrict__ xb_out,
    short* __restrict__ xzT_out,
    const short* __restrict__ WbcT,
    short* __restrict__ bcs)
{
    constexpr int RI = BM / 32;          // row frags per wave
    __shared__ short As[BM * 64];        // [row][64k], 128B rows
    __shared__ short Bs[128 * 64];       // [n][64k]

    const int tid = threadIdx.x;
    const int wave = tid >> 6, lane = tid & 63;
    const int kk = (lane >> 4) * 8;
    const int r16 = lane & 15;
    const int wr = wave >> 1, wc = wave & 1;

    if (FUSE_BC && blockIdx.x == gridDim.x - 1) {
        // ---- bc path: 32 rows x 32 cols, BK=64 ----
        const int bm2 = blockIdx.y * 32;
        f32x4 acc2 = {};
        for (int k0 = 0; k0 < K; k0 += 64) {
            int off = tid * 16;
            int row = off >> 7;            // 128B per row (64 bf16)
            int ke  = (off & 127) >> 1;
            gload_lds16(A + (size_t)(bm2 + row) * lda + k0 + ke, (char*)As + off);
            gload_lds16(WbcT + (size_t)row * K + k0 + ke, (char*)Bs + off);
            __syncthreads();
            bf16x8 alo = *(const bf16x8*)&As[(wr * 16 + r16) * 64 + kk];
            bf16x8 ahi = *(const bf16x8*)&As[(wr * 16 + r16) * 64 + kk + 32];
            bf16x8 blo = *(const bf16x8*)&Bs[(wc * 16 + r16) * 64 + kk];
            bf16x8 bhi = *(const bf16x8*)&Bs[(wc * 16 + r16) * 64 + kk + 32];
            acc2 = __builtin_amdgcn_mfma_f32_16x16x32_bf16(alo, blo, acc2, 0, 0, 0);
            acc2 = __builtin_amdgcn_mfma_f32_16x16x32_bf16(ahi, bhi, acc2, 0, 0, 0);
            __syncthreads();
        }
        #pragma unroll
        for (int g = 0; g < 4; g++) {
            int row = bm2 + wr * 16 + (lane >> 4) * 4 + g;
            int col = wc * 16 + r16;
            int bb = row >> 10, t = row & 1023;
            int j = t & 3, c = t >> 2;
            bcs[(size_t)(((bb << 2) | j) * NCH + c) * 32 + col] = f2bf(acc2[g]);
        }
        return;
    }

    const int bm = blockIdx.y * BM, bn = blockIdx.x * 128;
    f32x4 acc[RI][4] = {};

    for (int k0 = 0; k0 < K; k0 += 64) {
        // stage B tile: 16384B, 4 x 16B per thread
        #pragma unroll
        for (int it = 0; it < 4; it++) {
            int off = it * 4096 + tid * 16;
            int row = off >> 7;             // 128B per row (64 bf16)
            int ke  = (off & 127) >> 1;
            gload_lds16(BT + (size_t)(bn + row) * ldb + k0 + ke, (char*)Bs + off);
        }
        // stage A tile: BM*128 bytes (BM=32 -> 4096B, 1 x 16B per thread)
        if (tid < BM * 8) {
            int off = tid * 16;
            int row = off >> 7;
            int ke  = (off & 127) >> 1;
            gload_lds16(A + (size_t)(bm + row) * lda + k0 + ke, (char*)As + off);
        }
        __syncthreads();

        #pragma unroll
        for (int ks = 0; ks < 64; ks += 32) {
            bf16x8 a[RI], b[4];
            #pragma unroll
            for (int i = 0; i < RI; i++)
                a[i] = *(const bf16x8*)&As[(wr * (BM / 2) + i * 16 + r16) * 64 + ks + kk];
            #pragma unroll
            for (int j = 0; j < 4; j++)
                b[j] = *(const bf16x8*)&Bs[(wc * 64 + j * 16 + r16) * 64 + ks + kk];
            #pragma unroll
            for (int i = 0; i < RI; i++)
                #pragma unroll
                for (int j = 0; j < 4; j++)
                    acc[i][j] = __builtin_amdgcn_mfma_f32_16x16x32_bf16(
                        a[i], b[j], acc[i][j], 0, 0, 0);
        }
        __syncthreads();
    }

    // epilogue: C/D layout col = lane&15, row = (lane>>4)*4 + reg (m89/m91)
    #pragma unroll
    for (int i = 0; i < RI; i++) {
        #pragma unroll
        for (int j = 0; j < 4; j++) {
            int row0 = bm + wr * (BM / 2) + i * 16 + (lane >> 4) * 4;
            int col = bn + wc * 64 + j * 16 + r16;
            if (EPI == 3) {
                short4 p;
                #pragma unroll
                for (int g = 0; g < 4; g++) {
                    short h = f2bf(acc[i][j][g]);
                    ((short*)&p)[g] = h;
                    if (col < DD) xb_out[(size_t)(row0 + g) * DD + col] = h;
                }
                *(short4*)&xzT_out[(size_t)col * 2048 + row0] = p;
            } else {
                #pragma unroll
                for (int g = 0; g < 4; g++) {
                    int row = row0 + g;
                    float v = acc[i][j][g];
                    if (EPI == 4) {
                        v += bias[row];
                        v = fmaxf(v, 0.f) + log1pf(__expf(-fabsf(v)));
                    }
                    if (EPI == 2) {
                        v -= sub[(size_t)row * ldc + col];
                    }
                    C[(size_t)row * ldc + col] = v;
                }
            }
        }
    }
}

// ---------------------------------------------------------------------------
// 32x32 fp32->bf16 transpose tile (shared helper for prep kernel)
// ---------------------------------------------------------------------------
__device__ __forceinline__ void tr_tile(
    const float* __restrict__ W, short* __restrict__ WT,
    int K, int N, int k0, int n0, int tid)
{
    __shared__ float t[32][33];
    int r = tid >> 3, q = tid & 7;
    float4 v = *(const float4*)&W[(size_t)(k0 + r) * N + n0 + q * 4];
    t[r][q * 4 + 0] = v.x; t[r][q * 4 + 1] = v.y;
    t[r][q * 4 + 2] = v.z; t[r][q * 4 + 3] = v.w;
    __syncthreads();
    short4 o = { f2bf(t[q * 4 + 0][r]), f2bf(t[q * 4 + 1][r]),
                 f2bf(t[q * 4 + 2][r]), f2bf(t[q * 4 + 3][r]) };
    *(short4*)&WT[(size_t)(n0 + r) * K + k0 + q * 4] = o;
}

// ---------------------------------------------------------------------------
// One-shot prep: all fp32->bf16 converts/transposes in a single launch.
// ---------------------------------------------------------------------------
__global__ __launch_bounds__(256) void prep_all(
    const float* __restrict__ H,    short* __restrict__ Hb,
    const float* __restrict__ W_xz, short* __restrict__ WxzT,
    const float* __restrict__ W_dt, short* __restrict__ WdtT,
    const float* __restrict__ W_out,short* __restrict__ WoutT,
    const float* __restrict__ W_B,  const float* __restrict__ W_C,
    short* __restrict__ WbcT)
{
    int bid = blockIdx.x, tid = threadIdx.x;
    if (bid < 2048) {
        int i = bid * 1024 + tid * 4;
        float4 v = *(const float4*)&H[i];
        short4 o = { f2bf(v.x), f2bf(v.y), f2bf(v.z), f2bf(v.w) };
        *(short4*)&Hb[i] = o;
    } else if (bid < 4096) {
        int t = bid - 2048;                       // 64 n-tiles x 32 k-tiles
        tr_tile(W_xz, WxzT, DD, 2 * DD, (t >> 6) * 32, (t & 63) * 32, tid);
    } else if (bid < 5120) {
        int t = bid - 4096;
        tr_tile(W_dt, WdtT, DD, DD, (t >> 5) * 32, (t & 31) * 32, tid);
    } else if (bid < 6144) {
        int t = bid - 5120;
        tr_tile(W_out, WoutT, DD, DD, (t >> 5) * 32, (t & 31) * 32, tid);
    } else {
        int g = (bid - 6144) * 256 + tid;         // 0..32767
        int k = g & (DD - 1);
        int n = g >> 10;
        float v = (n < 16) ? W_B[(size_t)k * NN + n]
                           : W_C[(size_t)k * NN + n - 16];
        WbcT[(size_t)n * DD + k] = f2bf(v);
    }
}

// ---------------------------------------------------------------------------
// bf16 transpose: gT[1024 d][2048 bt] -> gb[2048 bt][1024 d].  64x64 tiles.
// ---------------------------------------------------------------------------
__global__ __launch_bounds__(256) void tr_g(
    const short* __restrict__ gT, short* __restrict__ gb)
{
    __shared__ short L[64][72];   // 72-short stride keeps 16B alignment
    const int bt0 = blockIdx.x * 64, d0 = blockIdx.y * 64;
    const int tid = threadIdx.x;
    const int r = tid >> 3, c8 = (tid & 7) * 8;
    #pragma unroll
    for (int p = 0; p < 2; p++) {
        int dd = r + p * 32;
        *(int4*)&L[dd][c8] = *(const int4*)&gT[(size_t)(d0 + dd) * 2048 + bt0 + c8];
    }
    __syncthreads();
    #pragma unroll
    for (int p = 0; p < 2; p++) {
        int tb = r + p * 32;
        short tmp[8];
        #pragma unroll
        for (int k = 0; k < 8; k++) tmp[k] = L[c8 + k][tb];
        *(int4*)&gb[(size_t)(bt0 + tb) * DD + d0 + c8] = *(int4*)&tmp[0];
    }
}

// ---------------------------------------------------------------------------
// Fused scan v7: LCH=4/NCH=256 + swizzled bf16 bc + native exp2.
// Block: 512 threads = 2 d-lanes x 256 chunks; grid (DD/2, BB) = 1024 blocks
// -> 4 blocks/CU (LDS 40960B x 4 = 160KiB exact), 8 waves/SIMD.
// ---------------------------------------------------------------------------
__global__ __launch_bounds__(512) void scan_fused7(
    const float* __restrict__ dtT,    // [1024 d][2048 bt] fp32 (post-softplus)
    const short* __restrict__ xzT,    // [2048 e][2048 bt] bf16
    const short* __restrict__ bcs,    // [b][4][256][32] bf16 (B|C swizzled)
    const float* __restrict__ A_log,  // [1024][16]
    const float* __restrict__ D_skip,
    const float* __restrict__ v_th,
    short* __restrict__ gT)           // [1024 d][2048 bt] bf16
{
    __shared__ float Ls[512 * 17];        // 34816 B; Sinit in-place
    __shared__ float Sd[512];             // 2048 B: per-chunk sum(dt)
    __shared__ float Gp[16][2][16];       // 2048 B: group decay, then Gi in-place
    __shared__ float Gl[16][2][16];       // 2048 B: group local state
                                          // total 40960 B -> 4 blocks/CU

    const int tid = threadIdx.x;
    const int dl = tid & 1;
    const int c  = tid >> 1;               // chunk 0..255
    const int d  = blockIdx.x * 2 + dl;
    const int b  = blockIdx.y;
    const int R0 = b * TT + c * LCH;        // global bt base

    float a2[NN];
    #pragma unroll
    for (int n = 0; n < NN; n++)
        a2[n] = -__expf(A_log[(size_t)d * NN + n]) * L2E;

    // contiguous per-thread stream preloads (16B dt, 8B x, 8B z)
    float dtv[LCH];
    *(float4*)&dtv[0] = *(const float4*)&dtT[(size_t)d * 2048 + R0];
    short xv[LCH], zv[LCH];
    *(int2*)&xv[0] = *(const int2*)&xzT[(size_t)d * 2048 + R0];
    *(int2*)&zv[0] = *(const int2*)&xzT[(size_t)(DD + d) * 2048 + R0];

    // ---- phase 1: local chunk scan (s0 = 0) ----
    float s[NN];
    #pragma unroll
    for (int n = 0; n < NN; n++) s[n] = 0.f;
    float sum_dt = 0.f;

    #pragma unroll
    for (int j = 0; j < LCH; j++) {
        float dt = dtv[j];
        float x  = bf2f(xv[j]);
        float dtx = dt * x;
        sum_dt += dt;
        const short* bp = &bcs[(size_t)(((b << 2) | j) * NCH + c) * 32];
        short bB[NN];
        *(int4*)&bB[0] = *(const int4*)&bp[0];
        *(int4*)&bB[8] = *(const int4*)&bp[8];
        #pragma unroll
        for (int n = 0; n < NN; n++) {
            float dec = EXP2(a2[n] * dt);
            s[n] = fmaf(dec, s[n], dtx * bf2f(bB[n]));
        }
    }
    #pragma unroll
    for (int n = 0; n < NN; n++) Ls[tid * 17 + n] = s[n];
    Sd[tid] = sum_dt;
    __syncthreads();

    // ---- phase 2: hierarchical combine (16 groups x 16 chunks) ----
    {
        int dl2 = tid & 1, n2 = (tid >> 1) & 15, sg = tid >> 5;
        float a2n = -__expf(A_log[(size_t)(blockIdx.x * 2 + dl2) * NN + n2]) * L2E;
        float Pg = 1.f, Lg = 0.f;
        for (int k = 0; k < 16; k++) {
            int lt = (sg * 16 + k) * 2 + dl2;
            float P = EXP2(a2n * Sd[lt]);
            float L = Ls[lt * 17 + n2];
            Lg = fmaf(P, Lg, L);
            Pg *= P;
        }
        Gp[sg][dl2][n2] = Pg; Gl[sg][dl2][n2] = Lg;
        __syncthreads();
        if (tid < 32) {
            int dl3 = tid & 1, n3 = tid >> 1;
            float Sg = 0.f;
            for (int g = 0; g < 16; g++) {
                float Pgv = Gp[g][dl3][n3];
                Gp[g][dl3][n3] = Sg;          // Gi overwrites Gp (read-first)
                Sg = fmaf(Pgv, Sg, Gl[g][dl3][n3]);
            }
        }
        __syncthreads();
        float ss = Gp[sg][dl2][n2];           // group-init state
        for (int k = 0; k < 16; k++) {
            int lt = (sg * 16 + k) * 2 + dl2;
            float P = EXP2(a2n * Sd[lt]);
            float L = Ls[lt * 17 + n2];
            Ls[lt * 17 + n2] = ss;            // Sinit overwrites (read-first)
            ss = fmaf(P, ss, L);
        }
    }
    __syncthreads();

    // ---- phase 3: replay with correct init + gate epilogue ----
    #pragma unroll
    for (int n = 0; n < NN; n++) s[n] = Ls[tid * 17 + n];

    const float dsk = D_skip[d];
    const float vth = fmaxf(v_th[d], V_TH_MIN);
    const float KL2 = K_STEEP * L2E;
    short gvv[LCH];

    #pragma unroll
    for (int j = 0; j < LCH; j++) {
        float dt = dtv[j];
        float x  = bf2f(xv[j]);
        float z  = bf2f(zv[j]);
        float dtx = dt * x;
        const short* bp = &bcs[(size_t)(((b << 2) | j) * NCH + c) * 32];
        short bB[NN], bC[NN];
        *(int4*)&bB[0] = *(const int4*)&bp[0];
        *(int4*)&bB[8] = *(const int4*)&bp[8];
        *(int4*)&bC[0] = *(const int4*)&bp[16];
        *(int4*)&bC[8] = *(const int4*)&bp[24];
        float y = 0.f;
        #pragma unroll
        for (int n = 0; n < NN; n++) {
            float dec = EXP2(a2[n] * dt);
            s[n] = fmaf(dec, s[n], dtx * bf2f(bB[n]));
            y = fmaf(s[n], bf2f(bC[n]), y);
        }
        y = fmaf(dsk, x, y);
        float sp = 1.f / (1.f + EXP2(-KL2 * (y - vth)));
        float sz = z / (1.f + EXP2(-z * L2E));
        gvv[j] = f2bf(y * sp * sz);
    }

    // one 8B contiguous store per thread
    *(int2*)&gT[(size_t)d * 2048 + R0] = *(const int2*)&gvv[0];
}

// ---------------------------------------------------------------------------
extern "C" void kernel_launch(void* const* d_in, const int* in_sizes, int n_in,
                              void* d_out, int out_size, void* d_ws, size_t ws_size,
                              hipStream_t stream) {
    const float* H      = (const float*)d_in[0];   // (2,1024,1024)
    const float* W_xz   = (const float*)d_in[1];   // (1024,2048)
    const float* W_dt   = (const float*)d_in[2];   // (1024,1024)
    const float* b_dt   = (const float*)d_in[3];   // (1024,)
    const float* A_log  = (const float*)d_in[4];   // (1024,16)
    const float* W_B    = (const float*)d_in[5];   // (1024,16)
    const float* W_C    = (const float*)d_in[6];   // (1024,16)
    const float* D_skip = (const float*)d_in[7];   // (1024,)
    const float* W_out  = (const float*)d_in[8];   // (1024,1024)
    const float* v_th   = (const float*)d_in[9];   // (1024,)
    float* out = (float*)d_out;

    // flat ws layout (~42 MB of 268 MB) — no aliasing
    float* ws  = (float*)d_ws;
    float* dtT = ws;                   // 1024*2048 f
    short* p16   = (short*)(dtT + 2097152);
    short* bcs   = p16;                // 2*4*256*32 = 65536 s (bf16, swizzled)
    short* xzT   = bcs   + 65536;      // 2048*2048 s  (xT | zT)
    short* xb    = xzT   + 4194304;    // 2048*1024 s  (x row-major, for G2)
    short* Hb    = xb    + 2097152;    // 2097152 s
    short* WxzT  = Hb    + 2097152;    // 2097152 s
    short* WdtT  = WxzT  + 2097152;    // 1048576 s
    short* WoutT = WdtT  + 1048576;    // 1048576 s
    short* WbcT  = WoutT + 1048576;    // 32768 s
    short* gT    = WbcT  + 32768;      // 1024*2048 s (g transposed)
    short* gb    = gT    + 2097152;    // 2048*1024 s (g row-major)

    const int M = BB * TT;  // 2048

    // 0) all converts in one launch
    prep_all<<<6272, 256, 0, stream>>>(
        H, Hb, W_xz, WxzT, W_dt, WdtT, W_out, WoutT, W_B, W_C, WbcT);
    // 1) xz = H @ W_xz: writes xb + xzT, + swizzled bf16 bc
    gemm_mfma<32, 3, true><<<dim3(17, M / 32), 256, 0, stream>>>(
        Hb, DD, WxzT, DD, nullptr, 0, M, 2 * DD, DD,
        nullptr, nullptr, xb, xzT, WbcT, bcs);
    // 2) dtT = softplus(W_dt^T @ x^T + b_dt[row]): swapped GEMM, M=1024, N=2048
    gemm_mfma<32, 4, false><<<dim3(M / 128, DD / 32), 256, 0, stream>>>(
        WdtT, DD, xb, DD, dtT, M, DD, M, DD,
        b_dt, nullptr, nullptr, nullptr, nullptr, nullptr);
    // 3) fused chunked scan (LCH=4, 1024 blocks, 4/CU, native exp2)
    scan_fused7<<<dim3(DD / 2, BB), 512, 0, stream>>>(
        dtT, xzT, bcs, A_log, D_skip, v_th, gT);
    // 3b) transpose gT -> gb (row-major for G3's A operand)
    tr_g<<<dim3(2048 / 64, DD / 64), 256, 0, stream>>>(gT, gb);
    // 4) out = g @ W_out - H
    gemm_mfma<32, 2, false><<<dim3(DD / 128, M / 32), 256, 0, stream>>>(
        gb, DD, WoutT, DD, out, DD, M, DD, DD,
        nullptr, H, nullptr, nullptr, nullptr, nullptr);
}